// Round 1
// baseline (115.716 us; speedup 1.0000x reference)
//
#include <hip/hip_runtime.h>

typedef unsigned short u16;
typedef unsigned int   u32;
typedef __attribute__((ext_vector_type(8))) short short8;
typedef __attribute__((ext_vector_type(4))) float f32x4;

__device__ __forceinline__ u16 f2bf(float f) {
    u32 u = __float_as_uint(f);
    u = (u + 0x7fffu + ((u >> 16) & 1u)) >> 16;
    return (u16)u;
}

__device__ __forceinline__ void gld_lds16(const void* g, void* l) {
    __builtin_amdgcn_global_load_lds(
        (const __attribute__((address_space(1))) u32*)g,
        (__attribute__((address_space(3))) u32*)l, 16, 0, 0);
}

// ---------------------------------------------------------------------------
// K1a: cast adj (1M) + wct (2M) fp32 -> bf16, contiguous dst [Ab | W0b | W1b]
// ---------------------------------------------------------------------------
__global__ __launch_bounds__(256) void cast_bf16_kernel(
    const float* __restrict__ adj, const float* __restrict__ wct,
    u16* __restrict__ dst)
{
    const int i4 = blockIdx.x * 256 + threadIdx.x;   // float4 index, 0..786431
    const float4 v = (i4 < 262144) ? ((const float4*)adj)[i4]
                                   : ((const float4*)wct)[i4 - 262144];
    ushort4 o;
    o.x = f2bf(v.x); o.y = f2bf(v.y); o.z = f2bf(v.z); o.w = f2bf(v.w);
    ((ushort4*)dst)[i4] = o;
}

// ---------------------------------------------------------------------------
// K1b/K1c: transpose+cast  src (RxC fp32, row-major) -> dst (CxR bf16)
// 64x64 tiles via LDS. grid = (R/64, C/64)
// ---------------------------------------------------------------------------
__global__ __launch_bounds__(256) void transpose_cast(
    const float* __restrict__ src, u16* __restrict__ dst, int C, int R)
{
    __shared__ float tile[64][65];
    const int t  = threadIdx.x;
    const int r0 = blockIdx.x << 6;   // src row tile
    const int c0 = blockIdx.y << 6;   // src col tile
#pragma unroll
    for (int it = 0; it < 4; ++it) {
        const int f4 = it * 256 + t;            // 0..1023
        const int r  = f4 >> 4;                 // 0..63
        const int c4 = (f4 & 15) << 2;
        const float4 v = *(const float4*)&src[(size_t)(r0 + r) * C + c0 + c4];
        tile[r][c4]     = v.x; tile[r][c4 + 1] = v.y;
        tile[r][c4 + 2] = v.z; tile[r][c4 + 3] = v.w;
    }
    __syncthreads();
#pragma unroll
    for (int it = 0; it < 4; ++it) {
        const int f4 = it * 256 + t;
        const int u  = f4 >> 4;                 // dst row offset (src col)
        const int v4 = (f4 & 15) << 2;          // dst col offset (src row)
        ushort4 o;
        o.x = f2bf(tile[v4][u]);     o.y = f2bf(tile[v4 + 1][u]);
        o.z = f2bf(tile[v4 + 2][u]); o.w = f2bf(tile[v4 + 3][u]);
        *(ushort4*)&dst[(size_t)(c0 + u) * R + r0 + v4] = o;
    }
}

// ---------------------------------------------------------------------------
// K2: block-sparse MFMA GEMM  H(3072x2048 bf16) = local_adj @ X
// m97 structure: 128x128 tile, BK=32, 4 waves (2x2), global_load_lds staging,
// linear LDS [row][32], 16x16x32 bf16 MFMA, 2 barriers per K-step.
// grid = (24 M-tiles, 16 N-tiles)
// ---------------------------------------------------------------------------
__global__ __launch_bounds__(256) void gemm_h_kernel(
    const u16* __restrict__ Ab,  const u16* __restrict__ W0b,
    const u16* __restrict__ W1b, const u16* __restrict__ W0T,
    const u16* __restrict__ W1T, const u16* __restrict__ Xt,
    u16* __restrict__ H)
{
    __shared__ u16 Asm[128 * 32];   // [row][k]
    __shared__ u16 Bsm[128 * 32];   // [col][k]  (cols of X = rows of Xt)

    const int tid  = threadIdx.x;
    const int mt   = blockIdx.x;            // 0..23
    const int nt   = blockIdx.y;            // 0..15
    const int i    = mt >> 3;               // block-row 0..2
    const int row0 = (mt & 7) << 7;         // row offset within 1024-block
    const int col0 = nt << 7;

    const int l    = tid & 63;
    const int wr   = ((tid >> 7) & 1) << 6; // wave row offset (0/64)
    const int wc   = ((tid >> 6) & 1) << 6; // wave col offset (0/64)
    const int lrow = l & 15;
    const int kgrp = (l >> 4) << 3;

    // staging decomposition: flat16 = L*256 + tid ; row = flat16/4, k = (flat16%4)*8
    const int arow = tid >> 2;              // 0..63 (L=0)
    const int koff = (tid & 3) << 3;
    u16* AsmW = Asm + ((tid & ~63) << 3);   // wave-uniform LDS base (elements)
    u16* BsmW = Bsm + ((tid & ~63) << 3);

    f32x4 acc[4][4] = {};

    auto run_term = [&](const u16* __restrict__ Amat, const u16* __restrict__ Bmat) {
        for (int k0 = 0; k0 < 1024; k0 += 32) {
            const u16* ga = Amat + (size_t)arow * 1024 + k0 + koff;
            gld_lds16(ga,              AsmW);
            gld_lds16(ga + 64 * 1024,  AsmW + 2048);
            const u16* gb = Bmat + (size_t)arow * 3072 + k0 + koff;
            gld_lds16(gb,              BsmW);
            gld_lds16(gb + 64 * 3072,  BsmW + 2048);
            __syncthreads();

            short8 af[4], bfr[4];
#pragma unroll
            for (int fm = 0; fm < 4; ++fm)
                af[fm] = *(const short8*)&Asm[(wr + fm * 16 + lrow) * 32 + kgrp];
#pragma unroll
            for (int fn = 0; fn < 4; ++fn)
                bfr[fn] = *(const short8*)&Bsm[(wc + fn * 16 + lrow) * 32 + kgrp];
#pragma unroll
            for (int fm = 0; fm < 4; ++fm)
#pragma unroll
                for (int fn = 0; fn < 4; ++fn)
                    acc[fm][fn] = __builtin_amdgcn_mfma_f32_16x16x32_bf16(
                        af[fm], bfr[fn], acc[fm][fn], 0, 0, 0);
            __syncthreads();
        }
    };

    const size_t xbase = (size_t)col0 * 3072;
    if (i == 0) {
        run_term(Ab  + row0 * 1024, Xt + xbase);
        run_term(W0b + row0 * 1024, Xt + xbase + 1024);
    } else if (i == 1) {
        run_term(W0T + row0 * 1024, Xt + xbase);
        run_term(Ab  + row0 * 1024, Xt + xbase + 1024);
        run_term(W1b + row0 * 1024, Xt + xbase + 2048);
    } else {
        run_term(W1T + row0 * 1024, Xt + xbase + 1024);
        run_term(Ab  + row0 * 1024, Xt + xbase + 2048);
    }

    // epilogue: D lane mapping col = lane&15, row = (lane>>4)*4 + r
    const int rbase = (l >> 4) << 2;
#pragma unroll
    for (int fm = 0; fm < 4; ++fm)
#pragma unroll
        for (int fn = 0; fn < 4; ++fn)
#pragma unroll
            for (int r = 0; r < 4; ++r) {
                const int grow = i * 1024 + row0 + wr + fm * 16 + rbase + r;
                const int gcol = col0 + wc + fn * 16 + lrow;
                H[(size_t)grow * 2048 + gcol] = f2bf(acc[fm][fn][r]);
            }
}

// ---------------------------------------------------------------------------
// K3: out(n,b,c) = (h@W + bias) GLU.  One block per n (3072 blocks).
// W (64x128 fp32) + h row (32x64 bf16) in LDS; fp32 VALU dot products.
// Thread t: c = t&63 (fixed W columns c, c+64), b = bq*8..bq*8+7 (bq = t>>6).
// ---------------------------------------------------------------------------
__global__ __launch_bounds__(256) void glu_kernel(
    const u16* __restrict__ H, const float* __restrict__ W,
    const float* __restrict__ bias, float* __restrict__ out)
{
    __shared__ float Wsm[8192];
    __shared__ u16   Hsm[2048];
    const int t = threadIdx.x;
    const int n = blockIdx.x;
#pragma unroll
    for (int it = 0; it < 8; ++it) {
        const int i4 = it * 256 + t;
        *(float4*)&Wsm[i4 * 4] = *(const float4*)&W[i4 * 4];
    }
    *(uint4*)&Hsm[t * 8] = *(const uint4*)&H[(size_t)n * 2048 + t * 8];
    __syncthreads();

    const int c  = t & 63;
    const int bq = t >> 6;
    const float bl = bias[c], br = bias[c + 64];
    float accL[8], accR[8];
#pragma unroll
    for (int j = 0; j < 8; ++j) { accL[j] = bl; accR[j] = br; }

    for (int k0 = 0; k0 < 64; k0 += 8) {
        float wl[8], wrg[8];
#pragma unroll
        for (int k = 0; k < 8; ++k) {
            wl[k]  = Wsm[(k0 + k) * 128 + c];
            wrg[k] = Wsm[(k0 + k) * 128 + c + 64];
        }
#pragma unroll
        for (int j = 0; j < 8; ++j) {
            const uint4 hv = *(const uint4*)&Hsm[(bq * 8 + j) * 64 + k0];
            const u32 wd[4] = {hv.x, hv.y, hv.z, hv.w};
            float hf[8];
#pragma unroll
            for (int q = 0; q < 4; ++q) {
                hf[2 * q]     = __uint_as_float(wd[q] << 16);
                hf[2 * q + 1] = __uint_as_float(wd[q] & 0xffff0000u);
            }
#pragma unroll
            for (int k = 0; k < 8; ++k) {
                accL[j] = fmaf(hf[k], wl[k],  accL[j]);
                accR[j] = fmaf(hf[k], wrg[k], accR[j]);
            }
        }
    }
#pragma unroll
    for (int j = 0; j < 8; ++j) {
        const float sg = 1.0f / (1.0f + __expf(-accR[j]));
        out[(size_t)n * 2048 + (bq * 8 + j) * 64 + c] = accL[j] * sg;
    }
}

// ---------------------------------------------------------------------------
extern "C" void kernel_launch(void* const* d_in, const int* in_sizes, int n_in,
                              void* d_out, int out_size, void* d_ws, size_t ws_size,
                              hipStream_t stream)
{
    const float* x    = (const float*)d_in[0];   // (3072, 32, 64)
    const float* adj  = (const float*)d_in[1];   // (1024, 1024)
    const float* wct  = (const float*)d_in[2];   // (2, 1024, 1024)
    const float* W    = (const float*)d_in[3];   // (64, 128)
    const float* bias = (const float*)d_in[4];   // (128,)
    float* out = (float*)d_out;

    char* ws = (char*)d_ws;
    // workspace layout (bytes):
    //   [0,        12582912)  Xt  bf16 [2048][3072]
    //   [12582912, 19 MB   )  Ab|W0b|W1b bf16 (3 x 1M)
    //   [18874368, 23068672)  W0T|W1T bf16 (2 x 1M)
    //   [23068672, 35651584)  H   bf16 [3072][2048]
    u16* Xt  = (u16*)ws;
    u16* Ab  = (u16*)(ws + 12582912);
    u16* W0b = Ab + 1048576;
    u16* W1b = Ab + 2097152;
    u16* W0T = (u16*)(ws + 18874368);
    u16* W1T = W0T + 1048576;
    u16* H   = (u16*)(ws + 23068672);

    cast_bf16_kernel<<<3072, 256, 0, stream>>>(adj, wct, Ab);
    transpose_cast<<<dim3(16, 16), 256, 0, stream>>>(wct,           W0T, 1024, 1024);
    transpose_cast<<<dim3(16, 16), 256, 0, stream>>>(wct + 1048576, W1T, 1024, 1024);
    transpose_cast<<<dim3(48, 32), 256, 0, stream>>>(x, Xt, 2048, 3072);

    gemm_h_kernel<<<dim3(24, 16), 256, 0, stream>>>(Ab, W0b, W1b, W0T, W1T, Xt, H);
    glu_kernel<<<3072, 256, 0, stream>>>(H, W, bias, out);
}

// Round 2
// 92.213 us; speedup vs baseline: 1.2549x; 1.2549x over previous
//
#include <hip/hip_runtime.h>

typedef unsigned short u16;
typedef unsigned int   u32;
typedef __attribute__((ext_vector_type(8))) short short8;
typedef __attribute__((ext_vector_type(4))) float f32x4;

__device__ __forceinline__ u16 f2bf(float f) {
    u32 u = __float_as_uint(f);
    u = (u + 0x7fffu + ((u >> 16) & 1u)) >> 16;
    return (u16)u;
}

__device__ __forceinline__ void gld_lds16(const void* g, void* l) {
    __builtin_amdgcn_global_load_lds(
        (const __attribute__((address_space(1))) u32*)g,
        (__attribute__((address_space(3))) u32*)l, 16, 0, 0);
}

// ---------------------------------------------------------------------------
// K1a: cast adj (1M) + wct (2M) fp32 -> bf16, contiguous dst [Ab | W0b | W1b]
// ---------------------------------------------------------------------------
__global__ __launch_bounds__(256) void cast_bf16_kernel(
    const float* __restrict__ adj, const float* __restrict__ wct,
    u16* __restrict__ dst)
{
    const int i4 = blockIdx.x * 256 + threadIdx.x;   // float4 index, 0..786431
    const float4 v = (i4 < 262144) ? ((const float4*)adj)[i4]
                                   : ((const float4*)wct)[i4 - 262144];
    ushort4 o;
    o.x = f2bf(v.x); o.y = f2bf(v.y); o.z = f2bf(v.z); o.w = f2bf(v.w);
    ((ushort4*)dst)[i4] = o;
}

// ---------------------------------------------------------------------------
// K1b/K1c: transpose+cast  src (RxC fp32, row-major) -> dst (CxR bf16)
// ---------------------------------------------------------------------------
__global__ __launch_bounds__(256) void transpose_cast(
    const float* __restrict__ src, u16* __restrict__ dst, int C, int R)
{
    __shared__ float tile[64][65];
    const int t  = threadIdx.x;
    const int r0 = blockIdx.x << 6;
    const int c0 = blockIdx.y << 6;
#pragma unroll
    for (int it = 0; it < 4; ++it) {
        const int f4 = it * 256 + t;
        const int r  = f4 >> 4;
        const int c4 = (f4 & 15) << 2;
        const float4 v = *(const float4*)&src[(size_t)(r0 + r) * C + c0 + c4];
        tile[r][c4]     = v.x; tile[r][c4 + 1] = v.y;
        tile[r][c4 + 2] = v.z; tile[r][c4 + 3] = v.w;
    }
    __syncthreads();
#pragma unroll
    for (int it = 0; it < 4; ++it) {
        const int f4 = it * 256 + t;
        const int u  = f4 >> 4;
        const int v4 = (f4 & 15) << 2;
        ushort4 o;
        o.x = f2bf(tile[v4][u]);     o.y = f2bf(tile[v4 + 1][u]);
        o.z = f2bf(tile[v4 + 2][u]); o.w = f2bf(tile[v4 + 3][u]);
        *(ushort4*)&dst[(size_t)(c0 + u) * R + r0 + v4] = o;
    }
}

// ---------------------------------------------------------------------------
// K2: block-sparse MFMA GEMM  H(3072x2048 bf16) = local_adj @ X
// Tile 64x128, BK=64, 4 waves (2Mx2N), grid = 768 blocks = 3/CU exact.
// LDS linear dest for global_load_lds; k-slot XOR-swizzle (slot ^ (row&7))
// applied to BOTH the global source and the ds_read (rule #21) -> no bank
// conflicts. XCD-chunked bijective block swizzle (4x2 XCD grid, 12x8 chunks).
// ---------------------------------------------------------------------------
__global__ __launch_bounds__(256, 3) void gemm_h_kernel(
    const u16* __restrict__ Ab,  const u16* __restrict__ W0b,
    const u16* __restrict__ W1b, const u16* __restrict__ W0T,
    const u16* __restrict__ W1T, const u16* __restrict__ Xt,
    u16* __restrict__ H)
{
    __shared__ u16 Asm[64 * 64];    // 8 KB  [row][8 slots of 16B], swizzled
    __shared__ u16 Bsm[128 * 64];   // 16 KB

    const int tid = threadIdx.x;

    // XCD-aware bijective swizzle: 768 blocks, xcd = bid&7 (round-robin),
    // XCDs arranged 4(M) x 2(N); each XCD owns a 12(mt) x 8(nt) chunk,
    // mt fastest within chunk so consecutive blocks share the B-panel.
    const int bid = blockIdx.x;
    const int xcd = bid & 7;
    const int idx = bid >> 3;              // 0..95
    const int mt  = (xcd & 3) * 12 + idx % 12;   // 0..47
    const int nt  = (xcd >> 2) * 8 + idx / 12;   // 0..15
    const int i    = mt >> 4;              // block-row 0..2
    const int row0 = (mt & 15) << 6;       // row offset within 1024-block
    const int col0 = nt << 7;

    const int l    = tid & 63;
    const int wr   = ((tid >> 7) & 1) << 5;  // wave M offset 0/32
    const int wc   = ((tid >> 6) & 1) << 6;  // wave N offset 0/64
    const int lrow = l & 15;
    const int g16  = l >> 4;                 // 0..3
    const int rsw  = lrow & 7;               // row&7 for all frag rows

    // staging: pass L covers rows L*32 + (tid>>3); 16B slot = tid&7;
    // global k pre-swizzled so the linear LDS write lands swizzled.
    const int sub  = tid >> 3;                       // 0..31
    const int srck = ((tid & 7) ^ (sub & 7)) << 3;   // element k offset in row
    u16* AsmW = Asm + ((tid >> 6) << 9);             // wave-uniform base
    u16* BsmW = Bsm + ((tid >> 6) << 9);

    f32x4 acc[2][4] = {};

    auto run_term = [&](const u16* __restrict__ Amat, const u16* __restrict__ Bmat) {
        for (int k0 = 0; k0 < 1024; k0 += 64) {
            const u16* ga = Amat + (size_t)sub * 1024 + k0 + srck;
            gld_lds16(ga,             AsmW);
            gld_lds16(ga + 32 * 1024, AsmW + 2048);
            const u16* gb = Bmat + (size_t)sub * 3072 + k0 + srck;
            gld_lds16(gb,             BsmW);
            gld_lds16(gb + 32 * 3072, BsmW + 2048);
            gld_lds16(gb + 64 * 3072, BsmW + 4096);
            gld_lds16(gb + 96 * 3072, BsmW + 6144);
            __syncthreads();

            short8 af[2][2], bfr[2][4];
#pragma unroll
            for (int kk = 0; kk < 2; ++kk) {
                const int so = (((kk << 2) | g16) ^ rsw) << 3;
#pragma unroll
                for (int fm = 0; fm < 2; ++fm)
                    af[kk][fm] = *(const short8*)&Asm[(wr + fm * 16 + lrow) * 64 + so];
#pragma unroll
                for (int fn = 0; fn < 4; ++fn)
                    bfr[kk][fn] = *(const short8*)&Bsm[(wc + fn * 16 + lrow) * 64 + so];
            }
#pragma unroll
            for (int kk = 0; kk < 2; ++kk)
#pragma unroll
                for (int fm = 0; fm < 2; ++fm)
#pragma unroll
                    for (int fn = 0; fn < 4; ++fn)
                        acc[fm][fn] = __builtin_amdgcn_mfma_f32_16x16x32_bf16(
                            af[kk][fm], bfr[kk][fn], acc[fm][fn], 0, 0, 0);
            __syncthreads();
        }
    };

    const size_t xbase = (size_t)col0 * 3072;
    if (i == 0) {
        run_term(Ab  + row0 * 1024, Xt + xbase);
        run_term(W0b + row0 * 1024, Xt + xbase + 1024);
    } else if (i == 1) {
        run_term(W0T + row0 * 1024, Xt + xbase);
        run_term(Ab  + row0 * 1024, Xt + xbase + 1024);
        run_term(W1b + row0 * 1024, Xt + xbase + 2048);
    } else {
        run_term(W1T + row0 * 1024, Xt + xbase + 1024);
        run_term(Ab  + row0 * 1024, Xt + xbase + 2048);
    }

    // epilogue: D lane mapping col = lane&15, row = (lane>>4)*4 + r
    const int rbase = g16 << 2;
#pragma unroll
    for (int fm = 0; fm < 2; ++fm)
#pragma unroll
        for (int fn = 0; fn < 4; ++fn)
#pragma unroll
            for (int r = 0; r < 4; ++r) {
                const int grow = i * 1024 + row0 + wr + fm * 16 + rbase + r;
                const int gcol = col0 + wc + fn * 16 + lrow;
                H[(size_t)grow * 2048 + gcol] = f2bf(acc[fm][fn][r]);
            }
}

// ---------------------------------------------------------------------------
// K3: out(n,b,c) = (h@W + bias) GLU.  One block per n (3072 blocks).
// ---------------------------------------------------------------------------
__global__ __launch_bounds__(256) void glu_kernel(
    const u16* __restrict__ H, const float* __restrict__ W,
    const float* __restrict__ bias, float* __restrict__ out)
{
    __shared__ float Wsm[8192];
    __shared__ u16   Hsm[2048];
    const int t = threadIdx.x;
    const int n = blockIdx.x;
#pragma unroll
    for (int it = 0; it < 8; ++it) {
        const int i4 = it * 256 + t;
        *(float4*)&Wsm[i4 * 4] = *(const float4*)&W[i4 * 4];
    }
    *(uint4*)&Hsm[t * 8] = *(const uint4*)&H[(size_t)n * 2048 + t * 8];
    __syncthreads();

    const int c  = t & 63;
    const int bq = t >> 6;
    const float bl = bias[c], br = bias[c + 64];
    float accL[8], accR[8];
#pragma unroll
    for (int j = 0; j < 8; ++j) { accL[j] = bl; accR[j] = br; }

    for (int k0 = 0; k0 < 64; k0 += 8) {
        float wl[8], wrg[8];
#pragma unroll
        for (int k = 0; k < 8; ++k) {
            wl[k]  = Wsm[(k0 + k) * 128 + c];
            wrg[k] = Wsm[(k0 + k) * 128 + c + 64];
        }
#pragma unroll
        for (int j = 0; j < 8; ++j) {
            const uint4 hv = *(const uint4*)&Hsm[(bq * 8 + j) * 64 + k0];
            const u32 wd[4] = {hv.x, hv.y, hv.z, hv.w};
            float hf[8];
#pragma unroll
            for (int q = 0; q < 4; ++q) {
                hf[2 * q]     = __uint_as_float(wd[q] << 16);
                hf[2 * q + 1] = __uint_as_float(wd[q] & 0xffff0000u);
            }
#pragma unroll
            for (int k = 0; k < 8; ++k) {
                accL[j] = fmaf(hf[k], wl[k],  accL[j]);
                accR[j] = fmaf(hf[k], wrg[k], accR[j]);
            }
        }
    }
#pragma unroll
    for (int j = 0; j < 8; ++j) {
        const float sg = 1.0f / (1.0f + __expf(-accR[j]));
        out[(size_t)n * 2048 + (bq * 8 + j) * 64 + c] = accL[j] * sg;
    }
}

// ---------------------------------------------------------------------------
extern "C" void kernel_launch(void* const* d_in, const int* in_sizes, int n_in,
                              void* d_out, int out_size, void* d_ws, size_t ws_size,
                              hipStream_t stream)
{
    const float* x    = (const float*)d_in[0];   // (3072, 32, 64)
    const float* adj  = (const float*)d_in[1];   // (1024, 1024)
    const float* wct  = (const float*)d_in[2];   // (2, 1024, 1024)
    const float* W    = (const float*)d_in[3];   // (64, 128)
    const float* bias = (const float*)d_in[4];   // (128,)
    float* out = (float*)d_out;

    char* ws = (char*)d_ws;
    u16* Xt  = (u16*)ws;                    // bf16 [2048][3072]
    u16* Ab  = (u16*)(ws + 12582912);       // 3 x 1M bf16
    u16* W0b = Ab + 1048576;
    u16* W1b = Ab + 2097152;
    u16* W0T = (u16*)(ws + 18874368);       // 2 x 1M bf16
    u16* W1T = W0T + 1048576;
    u16* H   = (u16*)(ws + 23068672);       // bf16 [3072][2048]

    cast_bf16_kernel<<<3072, 256, 0, stream>>>(adj, wct, Ab);
    transpose_cast<<<dim3(16, 16), 256, 0, stream>>>(wct,           W0T, 1024, 1024);
    transpose_cast<<<dim3(16, 16), 256, 0, stream>>>(wct + 1048576, W1T, 1024, 1024);
    transpose_cast<<<dim3(48, 32), 256, 0, stream>>>(x, Xt, 2048, 3072);

    gemm_h_kernel<<<768, 256, 0, stream>>>(Ab, W0b, W1b, W0T, W1T, Xt, H);
    glu_kernel<<<3072, 256, 0, stream>>>(H, W, bias, out);
}

// Round 3
// 59.911 us; speedup vs baseline: 1.9315x; 1.5392x over previous
//
#include <hip/hip_runtime.h>

typedef unsigned short u16;
typedef unsigned int   u32;
typedef __attribute__((ext_vector_type(8))) short short8;
typedef __attribute__((ext_vector_type(4))) float f32x4;

__device__ __forceinline__ u16 f2bf(float f) {
    u32 u = __float_as_uint(f);
    u = (u + 0x7fffu + ((u >> 16) & 1u)) >> 16;
    return (u16)u;
}

__device__ __forceinline__ void gld_lds16(const void* g, void* l) {
    __builtin_amdgcn_global_load_lds(
        (const __attribute__((address_space(1))) u32*)g,
        (__attribute__((address_space(3))) u32*)l, 16, 0, 0);
}

// ---------------------------------------------------------------------------
// prep: one launch, 5122 blocks.
//   [0,3072)      cast adj|wct fp32 -> bf16 into Ab|W0b|W1b
//   [3072,3328)   transpose+cast wct[0] -> W0T
//   [3328,3584)   transpose+cast wct[1] -> W1T
//   [3584,5120)   transpose+cast x (3072x2048) -> Xt (2048x3072)
//   [5120,5122)   transpose+cast W (64x128) -> Wt (128x64)
// ---------------------------------------------------------------------------
__global__ __launch_bounds__(256) void prep_kernel(
    const float* __restrict__ x, const float* __restrict__ adj,
    const float* __restrict__ wct, const float* __restrict__ W,
    u16* __restrict__ Ab, u16* __restrict__ W0T, u16* __restrict__ W1T,
    u16* __restrict__ Xt, u16* __restrict__ Wt)
{
    __shared__ float tile[64][65];
    const int t = threadIdx.x;
    const int bid = blockIdx.x;

    if (bid < 3072) {
        const int i4 = bid * 256 + t;
        const float4 v = (i4 < 262144) ? ((const float4*)adj)[i4]
                                       : ((const float4*)wct)[i4 - 262144];
        ushort4 o;
        o.x = f2bf(v.x); o.y = f2bf(v.y); o.z = f2bf(v.z); o.w = f2bf(v.w);
        ((ushort4*)Ab)[i4] = o;
        return;
    }

    const float* src; u16* dst; int C, R, r0, c0;
    if (bid < 3328)      { const int q = bid - 3072; src = wct;           dst = W0T; C = 1024; R = 1024; r0 = (q & 15) << 6; c0 = (q >> 4) << 6; }
    else if (bid < 3584) { const int q = bid - 3328; src = wct + 1048576; dst = W1T; C = 1024; R = 1024; r0 = (q & 15) << 6; c0 = (q >> 4) << 6; }
    else if (bid < 5120) { const int q = bid - 3584; src = x;             dst = Xt;  C = 2048; R = 3072; r0 = (q % 48) << 6; c0 = (q / 48) << 6; }
    else                 { const int q = bid - 5120; src = W;             dst = Wt;  C = 128;  R = 64;   r0 = 0;             c0 = q << 6; }

#pragma unroll
    for (int it = 0; it < 4; ++it) {
        const int f4 = it * 256 + t;
        const int r  = f4 >> 4;
        const int c4 = (f4 & 15) << 2;
        const float4 v = *(const float4*)&src[(size_t)(r0 + r) * C + c0 + c4];
        tile[r][c4]     = v.x; tile[r][c4 + 1] = v.y;
        tile[r][c4 + 2] = v.z; tile[r][c4 + 3] = v.w;
    }
    __syncthreads();
#pragma unroll
    for (int it = 0; it < 4; ++it) {
        const int f4 = it * 256 + t;
        const int u  = f4 >> 4;
        const int v4 = (f4 & 15) << 2;
        ushort4 o;
        o.x = f2bf(tile[v4][u]);     o.y = f2bf(tile[v4 + 1][u]);
        o.z = f2bf(tile[v4 + 2][u]); o.w = f2bf(tile[v4 + 3][u]);
        *(ushort4*)&dst[(size_t)(c0 + u) * R + r0 + v4] = o;
    }
}

// ---------------------------------------------------------------------------
// gemm+glu fused:  H-tile (64x128) = local_adj-blockrow @ X  via bf16 MFMA,
// then out-tile = GLU(H @ W + bias) in-register via a second MFMA pass.
// Tile 64x128, BK=64, 4 waves, 768 blocks = 3/CU.
// Balance: i = dispatch-round (idx/32) so each CU hosts i=0,1,2 concurrently.
// k-slot XOR swizzle on A/B (src-side, read-side) -> 0 bank conflicts.
// ---------------------------------------------------------------------------
__global__ __launch_bounds__(256, 3) void gemm_h_kernel(
    const u16* __restrict__ Ab,  const u16* __restrict__ W0b,
    const u16* __restrict__ W1b, const u16* __restrict__ W0T,
    const u16* __restrict__ W1T, const u16* __restrict__ Xt,
    const u16* __restrict__ Wt,  const float* __restrict__ bias,
    float* __restrict__ out)
{
    __shared__ u16 Asm[64 * 64];     // 8 KB
    __shared__ u16 Bsm[128 * 64];    // 16 KB (reused as Hsm in epilogue)
    __shared__ u16 Wsm[128 * 64];    // 16 KB, [c][cin] slot-swizzled
    __shared__ float Bias_sm[128];

    const int tid = threadIdx.x;
    const int bid = blockIdx.x;
    const int xcd = bid & 7;
    const int idx = bid >> 3;            // 0..95 within XCD
    const int i   = idx >> 5;            // dispatch round -> block-row 0..2
    const int idp = idx & 31;
    const int row0 = (idp & 15) << 6;    // mt' 0..15
    const int nt   = xcd * 2 + (idp >> 4);
    const int col0 = nt << 7;

    const int l    = tid & 63;
    const int w    = tid >> 6;               // wave 0..3
    const int wr   = ((tid >> 7) & 1) << 5;  // wave M offset 0/32
    const int wc   = ((tid >> 6) & 1) << 6;  // wave N offset 0/64
    const int lrow = l & 15;
    const int g16  = l >> 4;                 // 0..3
    const int rsw  = lrow & 7;

    // ---- stage Wt (swizzled src -> linear LDS) + bias; read only in epilogue
    {
        u16* wdst = Wsm + ((tid & ~63) << 3);
#pragma unroll
        for (int p = 0; p < 4; ++p) {
            const int flat = p * 256 + tid;
            const int row = flat >> 3, slot = flat & 7;
            gld_lds16(Wt + row * 64 + ((slot ^ (row & 7)) << 3), wdst + p * 2048);
        }
        if (tid < 128) Bias_sm[tid] = bias[tid];
    }

    // staging: sub-row = tid>>3 (0..31), 16B slot = tid&7, src k pre-swizzled
    const int sub  = tid >> 3;
    const int srck = ((tid & 7) ^ (sub & 7)) << 3;
    u16* AsmW = Asm + ((tid >> 6) << 9);
    u16* BsmW = Bsm + ((tid >> 6) << 9);

    f32x4 acc[2][4] = {};

    auto run_term = [&](const u16* __restrict__ Amat, const u16* __restrict__ Bmat) {
        for (int k0 = 0; k0 < 1024; k0 += 64) {
            const u16* ga = Amat + (size_t)sub * 1024 + k0 + srck;
            gld_lds16(ga,             AsmW);
            gld_lds16(ga + 32 * 1024, AsmW + 2048);
            const u16* gb = Bmat + (size_t)sub * 3072 + k0 + srck;
            gld_lds16(gb,             BsmW);
            gld_lds16(gb + 32 * 3072, BsmW + 2048);
            gld_lds16(gb + 64 * 3072, BsmW + 4096);
            gld_lds16(gb + 96 * 3072, BsmW + 6144);
            __syncthreads();

            short8 af[2][2], bfr[2][4];
#pragma unroll
            for (int kk = 0; kk < 2; ++kk) {
                const int so = (((kk << 2) | g16) ^ rsw) << 3;
#pragma unroll
                for (int fm = 0; fm < 2; ++fm)
                    af[kk][fm] = *(const short8*)&Asm[(wr + fm * 16 + lrow) * 64 + so];
#pragma unroll
                for (int fn = 0; fn < 4; ++fn)
                    bfr[kk][fn] = *(const short8*)&Bsm[(wc + fn * 16 + lrow) * 64 + so];
            }
#pragma unroll
            for (int kk = 0; kk < 2; ++kk)
#pragma unroll
                for (int fm = 0; fm < 2; ++fm)
#pragma unroll
                    for (int fn = 0; fn < 4; ++fn)
                        acc[fm][fn] = __builtin_amdgcn_mfma_f32_16x16x32_bf16(
                            af[kk][fm], bfr[kk][fn], acc[fm][fn], 0, 0, 0);
            __syncthreads();
        }
    };

    const size_t xbase = (size_t)col0 * 3072;
    if (i == 0) {
        run_term(Ab  + row0 * 1024, Xt + xbase);
        run_term(W0b + row0 * 1024, Xt + xbase + 1024);
    } else if (i == 1) {
        run_term(W0T + row0 * 1024, Xt + xbase);
        run_term(Ab  + row0 * 1024, Xt + xbase + 1024);
        run_term(W1b + row0 * 1024, Xt + xbase + 2048);
    } else {
        run_term(W1T + row0 * 1024, Xt + xbase + 1024);
        run_term(Ab  + row0 * 1024, Xt + xbase + 2048);
    }

    // ---- epilogue: Hsm = bf16(acc) (slot-swizzled), then out = GLU(H@W + b)
    u16* Hsm = Bsm;   // [n 64][col 128], slot' = (col>>3) ^ (n&7)
#pragma unroll
    for (int fm = 0; fm < 2; ++fm)
#pragma unroll
        for (int fn = 0; fn < 4; ++fn)
#pragma unroll
            for (int r = 0; r < 4; ++r) {
                const int n   = wr + fm * 16 + (g16 << 2) + r;
                const int col = wc + fn * 16 + lrow;
                const int sl2 = ((col >> 3) ^ (n & 7));
                Hsm[n * 128 + (sl2 << 3) + (col & 7)] = f2bf(acc[fm][fn][r]);
            }
    __syncthreads();

    // second GEMM: rows' = b*64+n (128), K = cin 64, N = 128 (lhs|rhs)
    f32x4 acc2[2][8];
#pragma unroll
    for (int fm2 = 0; fm2 < 2; ++fm2)
#pragma unroll
        for (int fn = 0; fn < 8; ++fn) {
            const float bv = Bias_sm[fn * 16 + lrow];
            acc2[fm2][fn] = (f32x4){bv, bv, bv, bv};
        }
#pragma unroll
    for (int kk = 0; kk < 2; ++kk) {
        const int gg = (kk << 2) | g16;      // cin group 0..7
        short8 ah[2], bw[8];
#pragma unroll
        for (int fm2 = 0; fm2 < 2; ++fm2) {
            const int rowp = (w << 5) + (fm2 << 4) + lrow;   // 0..127
            const int b = rowp >> 6, n = rowp & 63;
            const int sl2 = ((b << 3) | gg) ^ (n & 7);
            ah[fm2] = *(const short8*)&Hsm[n * 128 + (sl2 << 3)];
        }
#pragma unroll
        for (int fn = 0; fn < 8; ++fn) {
            const int c = (fn << 4) + lrow;
            const int sl2 = gg ^ (c & 7);
            bw[fn] = *(const short8*)&Wsm[c * 64 + (sl2 << 3)];
        }
#pragma unroll
        for (int fm2 = 0; fm2 < 2; ++fm2)
#pragma unroll
            for (int fn = 0; fn < 8; ++fn)
                acc2[fm2][fn] = __builtin_amdgcn_mfma_f32_16x16x32_bf16(
                    ah[fm2], bw[fn], acc2[fm2][fn], 0, 0, 0);
    }

    const int n0g = i * 1024 + row0;
    const int b0  = nt << 1;
#pragma unroll
    for (int fm2 = 0; fm2 < 2; ++fm2)
#pragma unroll
        for (int fn = 0; fn < 4; ++fn)
#pragma unroll
            for (int r = 0; r < 4; ++r) {
                const int rowp = (w << 5) + (fm2 << 4) + (g16 << 2) + r;
                const int b = rowp >> 6, nl = rowp & 63;
                const float lhs = acc2[fm2][fn][r];
                const float rhs = acc2[fm2][fn + 4][r];
                const float sg  = 1.0f / (1.0f + __expf(-rhs));
                const int c = (fn << 4) + lrow;
                out[((size_t)(n0g + nl) * 32 + (b0 + b)) * 64 + c] = lhs * sg;
            }
}

// ---------------------------------------------------------------------------
extern "C" void kernel_launch(void* const* d_in, const int* in_sizes, int n_in,
                              void* d_out, int out_size, void* d_ws, size_t ws_size,
                              hipStream_t stream)
{
    const float* x    = (const float*)d_in[0];   // (3072, 32, 64)
    const float* adj  = (const float*)d_in[1];   // (1024, 1024)
    const float* wct  = (const float*)d_in[2];   // (2, 1024, 1024)
    const float* W    = (const float*)d_in[3];   // (64, 128)
    const float* bias = (const float*)d_in[4];   // (128,)
    float* out = (float*)d_out;

    char* ws = (char*)d_ws;
    u16* Xt  = (u16*)ws;                    // bf16 [2048][3072]
    u16* Ab  = (u16*)(ws + 12582912);       // 3 x 1M bf16 (Ab|W0b|W1b)
    u16* W0b = Ab + 1048576;
    u16* W1b = Ab + 2097152;
    u16* W0T = (u16*)(ws + 18874368);       // 2 x 1M bf16
    u16* W1T = W0T + 1048576;
    u16* Wt  = (u16*)(ws + 23068672);       // bf16 [128][64]

    prep_kernel<<<5122, 256, 0, stream>>>(x, adj, wct, W, Ab, W0T, W1T, Xt, Wt);
    gemm_h_kernel<<<768, 256, 0, stream>>>(Ab, W0b, W1b, W0T, W1T, Xt, Wt, bias, out);
}

// Round 4
// 57.632 us; speedup vs baseline: 2.0078x; 1.0395x over previous
//
#include <hip/hip_runtime.h>

typedef unsigned short u16;
typedef unsigned int   u32;
typedef __attribute__((ext_vector_type(8))) short short8;
typedef __attribute__((ext_vector_type(4))) float f32x4;

__device__ __forceinline__ u16 f2bf(float f) {
    u32 u = __float_as_uint(f);
    u = (u + 0x7fffu + ((u >> 16) & 1u)) >> 16;
    return (u16)u;
}

__device__ __forceinline__ void gld_lds16(const void* g, void* l) {
    __builtin_amdgcn_global_load_lds(
        (const __attribute__((address_space(1))) u32*)g,
        (__attribute__((address_space(3))) u32*)l, 16, 0, 0);
}

// ---------------------------------------------------------------------------
// prep: one launch, 5122 blocks (cast + all transposes).
// ---------------------------------------------------------------------------
__global__ __launch_bounds__(256) void prep_kernel(
    const float* __restrict__ x, const float* __restrict__ adj,
    const float* __restrict__ wct, const float* __restrict__ W,
    u16* __restrict__ Ab, u16* __restrict__ W0T, u16* __restrict__ W1T,
    u16* __restrict__ Xt, u16* __restrict__ Wt)
{
    __shared__ float tile[64][65];
    const int t = threadIdx.x;
    const int bid = blockIdx.x;

    if (bid < 3072) {
        const int i4 = bid * 256 + t;
        const float4 v = (i4 < 262144) ? ((const float4*)adj)[i4]
                                       : ((const float4*)wct)[i4 - 262144];
        ushort4 o;
        o.x = f2bf(v.x); o.y = f2bf(v.y); o.z = f2bf(v.z); o.w = f2bf(v.w);
        ((ushort4*)Ab)[i4] = o;
        return;
    }

    const float* src; u16* dst; int C, R, r0, c0;
    if (bid < 3328)      { const int q = bid - 3072; src = wct;           dst = W0T; C = 1024; R = 1024; r0 = (q & 15) << 6; c0 = (q >> 4) << 6; }
    else if (bid < 3584) { const int q = bid - 3328; src = wct + 1048576; dst = W1T; C = 1024; R = 1024; r0 = (q & 15) << 6; c0 = (q >> 4) << 6; }
    else if (bid < 5120) { const int q = bid - 3584; src = x;             dst = Xt;  C = 2048; R = 3072; r0 = (q % 48) << 6; c0 = (q / 48) << 6; }
    else                 { const int q = bid - 5120; src = W;             dst = Wt;  C = 128;  R = 64;   r0 = 0;             c0 = q << 6; }

#pragma unroll
    for (int it = 0; it < 4; ++it) {
        const int f4 = it * 256 + t;
        const int r  = f4 >> 4;
        const int c4 = (f4 & 15) << 2;
        const float4 v = *(const float4*)&src[(size_t)(r0 + r) * C + c0 + c4];
        tile[r][c4]     = v.x; tile[r][c4 + 1] = v.y;
        tile[r][c4 + 2] = v.z; tile[r][c4 + 3] = v.w;
    }
    __syncthreads();
#pragma unroll
    for (int it = 0; it < 4; ++it) {
        const int f4 = it * 256 + t;
        const int u  = f4 >> 4;
        const int v4 = (f4 & 15) << 2;
        ushort4 o;
        o.x = f2bf(tile[v4][u]);     o.y = f2bf(tile[v4 + 1][u]);
        o.z = f2bf(tile[v4 + 2][u]); o.w = f2bf(tile[v4 + 3][u]);
        *(ushort4*)&dst[(size_t)(c0 + u) * R + r0 + v4] = o;
    }
}

// ---------------------------------------------------------------------------
// gemm+glu fused, 2-PHASE double-buffered pipeline:
//   per K-step: issue stage(next)->buf^1, ds_read+MFMA from buf, ONE barrier,
//   pointer swap. Prefetch crosses term boundaries. W staged into the A
//   double-buffer in the epilogue (LDS total 48.5 KB -> 3 blocks/CU).
// ---------------------------------------------------------------------------
__global__ __launch_bounds__(256, 3) void gemm_h_kernel(
    const u16* __restrict__ Ab,  const u16* __restrict__ W0b,
    const u16* __restrict__ W1b, const u16* __restrict__ W0T,
    const u16* __restrict__ W1T, const u16* __restrict__ Xt,
    const u16* __restrict__ Wt,  const float* __restrict__ bias,
    float* __restrict__ out)
{
    __shared__ u16 Adb[8192];     // 2 x 4096 elem (16 KB); epilogue: Wsm
    __shared__ u16 Bdb[16384];    // 2 x 8192 elem (32 KB); epilogue: Hsm
    __shared__ float Bias_sm[128];

    const int tid = threadIdx.x;
    const int bid = blockIdx.x;
    const int xcd = bid & 7;
    const int idx = bid >> 3;            // 0..95 within XCD
    const int i   = idx >> 5;            // dispatch round -> block-row 0..2
    const int idp = idx & 31;
    const int row0 = (idp & 15) << 6;
    const int nt   = xcd * 2 + (idp >> 4);
    const int col0 = nt << 7;

    const int l    = tid & 63;
    const int w    = tid >> 6;
    const int wr   = ((tid >> 7) & 1) << 5;  // wave M offset 0/32
    const int wc   = ((tid >> 6) & 1) << 6;  // wave N offset 0/64
    const int lrow = l & 15;
    const int g16  = l >> 4;
    const int rsw  = lrow & 7;

    const int sub  = tid >> 3;                       // 0..31
    const int srck = ((tid & 7) ^ (sub & 7)) << 3;   // pre-swizzled src k
    const int wofs = w << 9;                         // wave-uniform LDS base

    if (tid < 128) Bias_sm[tid] = bias[tid];

    u16 *Ac = Adb, *Ap = Adb + 4096, *Bc = Bdb, *Bp = Bdb + 8192;
    f32x4 acc[2][4] = {};

    auto stageA = [&](u16* dst, const u16* ta, int kel) {
        const u16* ga = ta + (size_t)sub * 1024 + kel + srck;
        gld_lds16(ga,             dst + wofs);
        gld_lds16(ga + 32 * 1024, dst + wofs + 2048);
    };
    auto stageB = [&](u16* dst, const u16* tb, int kel) {
        const u16* gb = tb + (size_t)sub * 3072 + kel + srck;
        gld_lds16(gb,             dst + wofs);
        gld_lds16(gb + 32 * 3072, dst + wofs + 2048);
        gld_lds16(gb + 64 * 3072, dst + wofs + 4096);
        gld_lds16(gb + 96 * 3072, dst + wofs + 6144);
    };
    auto step = [&](const u16* pfa, const u16* pfb, int kel, int do_pf) {
        if (do_pf) { stageA(Ap, pfa, kel); stageB(Bp, pfb, kel); }
        short8 af[2][2], bfr[2][4];
#pragma unroll
        for (int kk = 0; kk < 2; ++kk) {
            const int so = (((kk << 2) | g16) ^ rsw) << 3;
#pragma unroll
            for (int fm = 0; fm < 2; ++fm)
                af[kk][fm] = *(const short8*)&Ac[(wr + fm * 16 + lrow) * 64 + so];
#pragma unroll
            for (int fn = 0; fn < 4; ++fn)
                bfr[kk][fn] = *(const short8*)&Bc[(wc + fn * 16 + lrow) * 64 + so];
        }
#pragma unroll
        for (int kk = 0; kk < 2; ++kk)
#pragma unroll
            for (int fm = 0; fm < 2; ++fm)
#pragma unroll
                for (int fn = 0; fn < 4; ++fn)
                    acc[fm][fn] = __builtin_amdgcn_mfma_f32_16x16x32_bf16(
                        af[kk][fm], bfr[kk][fn], acc[fm][fn], 0, 0, 0);
        __syncthreads();
        u16* t;
        t = Ac; Ac = Ap; Ap = t;
        t = Bc; Bc = Bp; Bp = t;
    };
    auto run16 = [&](const u16* ta, const u16* tb,
                     const u16* na, const u16* nb, int hn) {
        for (int k = 1; k < 16; ++k) step(ta, tb, k << 6, 1);
        step(na, nb, 0, hn);
    };

    const size_t xbase = (size_t)col0 * 3072;
    const u16 *a0, *b0, *a1, *b1, *a2 = 0, *b2 = 0;
    int three = 0;
    if (i == 0) {
        a0 = Ab  + row0 * 1024; b0 = Xt + xbase;
        a1 = W0b + row0 * 1024; b1 = Xt + xbase + 1024;
    } else if (i == 1) {
        a0 = W0T + row0 * 1024; b0 = Xt + xbase;
        a1 = Ab  + row0 * 1024; b1 = Xt + xbase + 1024;
        a2 = W1b + row0 * 1024; b2 = Xt + xbase + 2048;
        three = 1;
    } else {
        a0 = W1T + row0 * 1024; b0 = Xt + xbase + 1024;
        a1 = Ab  + row0 * 1024; b1 = Xt + xbase + 2048;
    }

    stageA(Ac, a0, 0); stageB(Bc, b0, 0);
    __syncthreads();
    run16(a0, b0, a1, b1, 1);
    if (three) { run16(a1, b1, a2, b2, 1); run16(a2, b2, 0, 0, 0); }
    else       { run16(a1, b1, 0, 0, 0); }

    // ---- epilogue: Wsm <- Wt (into A dbuf), Hsm <- bf16(acc) (into B dbuf)
    u16* Wsm = Adb;
    u16* Hsm = Bdb;
#pragma unroll
    for (int p = 0; p < 4; ++p)
        gld_lds16(Wt + (size_t)(p * 32 + sub) * 64 + srck,
                  Adb + p * 2048 + wofs);
#pragma unroll
    for (int fm = 0; fm < 2; ++fm)
#pragma unroll
        for (int fn = 0; fn < 4; ++fn)
#pragma unroll
            for (int r = 0; r < 4; ++r) {
                const int n   = wr + fm * 16 + (g16 << 2) + r;
                const int col = wc + fn * 16 + lrow;
                const int sl2 = ((col >> 3) ^ (n & 7));
                Hsm[n * 128 + (sl2 << 3) + (col & 7)] = f2bf(acc[fm][fn][r]);
            }
    __syncthreads();

    // second GEMM: rows' = b*64+n (128), K = cin 64, N = 128 (lhs|rhs)
    f32x4 acc2[2][8];
#pragma unroll
    for (int fm2 = 0; fm2 < 2; ++fm2)
#pragma unroll
        for (int fn = 0; fn < 8; ++fn) {
            const float bv = Bias_sm[fn * 16 + lrow];
            acc2[fm2][fn] = (f32x4){bv, bv, bv, bv};
        }
#pragma unroll
    for (int kk = 0; kk < 2; ++kk) {
        const int gg = (kk << 2) | g16;
        short8 ah[2], bw[8];
#pragma unroll
        for (int fm2 = 0; fm2 < 2; ++fm2) {
            const int rowp = (w << 5) + (fm2 << 4) + lrow;
            const int b = rowp >> 6, n = rowp & 63;
            const int sl2 = ((b << 3) | gg) ^ (n & 7);
            ah[fm2] = *(const short8*)&Hsm[n * 128 + (sl2 << 3)];
        }
#pragma unroll
        for (int fn = 0; fn < 8; ++fn) {
            const int c = (fn << 4) + lrow;
            const int sl2 = gg ^ (c & 7);
            bw[fn] = *(const short8*)&Wsm[c * 64 + (sl2 << 3)];
        }
#pragma unroll
        for (int fm2 = 0; fm2 < 2; ++fm2)
#pragma unroll
            for (int fn = 0; fn < 8; ++fn)
                acc2[fm2][fn] = __builtin_amdgcn_mfma_f32_16x16x32_bf16(
                    ah[fm2], bw[fn], acc2[fm2][fn], 0, 0, 0);
    }

    const int n0g = i * 1024 + row0;
    const int b0i = nt << 1;
#pragma unroll
    for (int fm2 = 0; fm2 < 2; ++fm2)
#pragma unroll
        for (int fn = 0; fn < 4; ++fn)
#pragma unroll
            for (int r = 0; r < 4; ++r) {
                const int rowp = (w << 5) + (fm2 << 4) + (g16 << 2) + r;
                const int b = rowp >> 6, nl = rowp & 63;
                const float lhs = acc2[fm2][fn][r];
                const float rhs = acc2[fm2][fn + 4][r];
                const float sg  = 1.0f / (1.0f + __expf(-rhs));
                const int c = (fn << 4) + lrow;
                out[((size_t)(n0g + nl) * 32 + (b0i + b)) * 64 + c] = lhs * sg;
            }
}

// ---------------------------------------------------------------------------
extern "C" void kernel_launch(void* const* d_in, const int* in_sizes, int n_in,
                              void* d_out, int out_size, void* d_ws, size_t ws_size,
                              hipStream_t stream)
{
    const float* x    = (const float*)d_in[0];   // (3072, 32, 64)
    const float* adj  = (const float*)d_in[1];   // (1024, 1024)
    const float* wct  = (const float*)d_in[2];   // (2, 1024, 1024)
    const float* W    = (const float*)d_in[3];   // (64, 128)
    const float* bias = (const float*)d_in[4];   // (128,)
    float* out = (float*)d_out;

    char* ws = (char*)d_ws;
    u16* Xt  = (u16*)ws;                    // bf16 [2048][3072]
    u16* Ab  = (u16*)(ws + 12582912);       // 3 x 1M bf16 (Ab|W0b|W1b)
    u16* W0b = Ab + 1048576;
    u16* W1b = Ab + 2097152;
    u16* W0T = (u16*)(ws + 18874368);       // 2 x 1M bf16
    u16* W1T = W0T + 1048576;
    u16* Wt  = (u16*)(ws + 23068672);       // bf16 [128][64]

    prep_kernel<<<5122, 256, 0, stream>>>(x, adj, wct, W, Ab, W0T, W1T, Xt, Wt);
    gemm_h_kernel<<<768, 256, 0, stream>>>(Ab, W0b, W1b, W0T, W1T, Xt, Wt, bias, out);
}

// Round 5
// 56.154 us; speedup vs baseline: 2.0607x; 1.0263x over previous
//
#include <hip/hip_runtime.h>

typedef unsigned short u16;
typedef unsigned int   u32;
typedef __attribute__((ext_vector_type(8))) short short8;
typedef __attribute__((ext_vector_type(4))) float f32x4;

__device__ __forceinline__ u16 f2bf(float f) {
    u32 u = __float_as_uint(f);
    u = (u + 0x7fffu + ((u >> 16) & 1u)) >> 16;
    return (u16)u;
}

__device__ __forceinline__ void gld_lds16(const void* g, void* l) {
    __builtin_amdgcn_global_load_lds(
        (const __attribute__((address_space(1))) u32*)g,
        (__attribute__((address_space(3))) u32*)l, 16, 0, 0);
}

// ---------------------------------------------------------------------------
// prep: one launch, 5122 blocks (cast + all transposes).
// ---------------------------------------------------------------------------
__global__ __launch_bounds__(256) void prep_kernel(
    const float* __restrict__ x, const float* __restrict__ adj,
    const float* __restrict__ wct, const float* __restrict__ W,
    u16* __restrict__ Ab, u16* __restrict__ W0T, u16* __restrict__ W1T,
    u16* __restrict__ Xt, u16* __restrict__ Wt)
{
    __shared__ float tile[64][65];
    const int t = threadIdx.x;
    const int bid = blockIdx.x;

    if (bid < 3072) {
        const int i4 = bid * 256 + t;
        const float4 v = (i4 < 262144) ? ((const float4*)adj)[i4]
                                       : ((const float4*)wct)[i4 - 262144];
        ushort4 o;
        o.x = f2bf(v.x); o.y = f2bf(v.y); o.z = f2bf(v.z); o.w = f2bf(v.w);
        ((ushort4*)Ab)[i4] = o;
        return;
    }

    const float* src; u16* dst; int C, R, r0, c0;
    if (bid < 3328)      { const int q = bid - 3072; src = wct;           dst = W0T; C = 1024; R = 1024; r0 = (q & 15) << 6; c0 = (q >> 4) << 6; }
    else if (bid < 3584) { const int q = bid - 3328; src = wct + 1048576; dst = W1T; C = 1024; R = 1024; r0 = (q & 15) << 6; c0 = (q >> 4) << 6; }
    else if (bid < 5120) { const int q = bid - 3584; src = x;             dst = Xt;  C = 2048; R = 3072; r0 = (q % 48) << 6; c0 = (q / 48) << 6; }
    else                 { const int q = bid - 5120; src = W;             dst = Wt;  C = 128;  R = 64;   r0 = 0;             c0 = q << 6; }

#pragma unroll
    for (int it = 0; it < 4; ++it) {
        const int f4 = it * 256 + t;
        const int r  = f4 >> 4;
        const int c4 = (f4 & 15) << 2;
        const float4 v = *(const float4*)&src[(size_t)(r0 + r) * C + c0 + c4];
        tile[r][c4]     = v.x; tile[r][c4 + 1] = v.y;
        tile[r][c4 + 2] = v.z; tile[r][c4 + 3] = v.w;
    }
    __syncthreads();
#pragma unroll
    for (int it = 0; it < 4; ++it) {
        const int f4 = it * 256 + t;
        const int u  = f4 >> 4;
        const int v4 = (f4 & 15) << 2;
        ushort4 o;
        o.x = f2bf(tile[v4][u]);     o.y = f2bf(tile[v4 + 1][u]);
        o.z = f2bf(tile[v4 + 2][u]); o.w = f2bf(tile[v4 + 3][u]);
        *(ushort4*)&dst[(size_t)(c0 + u) * R + r0 + v4] = o;
    }
}

// ---------------------------------------------------------------------------
// gemm+glu fused, double-buffered with COUNTED vmcnt (T4):
//   per step: barrier(A); STAGE next->p; s_waitcnt vmcnt(6) [never 0 in the
//   main loop]; barrier(B); ds_read c + MFMA. Prefetch stays in flight
//   across the barriers -> no full drain stall.
// ---------------------------------------------------------------------------
__global__ __launch_bounds__(256, 3) void gemm_h_kernel(
    const u16* __restrict__ Ab,  const u16* __restrict__ W0b,
    const u16* __restrict__ W1b, const u16* __restrict__ W0T,
    const u16* __restrict__ W1T, const u16* __restrict__ Xt,
    const u16* __restrict__ Wt,  const float* __restrict__ bias,
    float* __restrict__ out)
{
    __shared__ u16 Adb[8192];     // 2 x 4096 elem (16 KB); epilogue: Wsm
    __shared__ u16 Bdb[16384];    // 2 x 8192 elem (32 KB); epilogue: Hsm
    __shared__ float Bias_sm[128];

    const int tid = threadIdx.x;
    const int bid = blockIdx.x;
    const int xcd = bid & 7;
    const int idx = bid >> 3;            // 0..95 within XCD
    const int i   = idx >> 5;            // dispatch round -> block-row 0..2
    const int idp = idx & 31;
    const int row0 = (idp & 15) << 6;
    const int nt   = xcd * 2 + (idp >> 4);
    const int col0 = nt << 7;

    const int l    = tid & 63;
    const int w    = tid >> 6;
    const int wr   = ((tid >> 7) & 1) << 5;  // wave M offset 0/32
    const int wc   = ((tid >> 6) & 1) << 6;  // wave N offset 0/64
    const int lrow = l & 15;
    const int g16  = l >> 4;
    const int rsw  = lrow & 7;

    const int sub  = tid >> 3;                       // 0..31
    const int srck = ((tid & 7) ^ (sub & 7)) << 3;   // pre-swizzled src k
    const int wofs = w << 9;                         // wave-uniform LDS base

    if (tid < 128) Bias_sm[tid] = bias[tid];

    u16 *Ac = Adb, *Ap = Adb + 4096, *Bc = Bdb, *Bp = Bdb + 8192;
    f32x4 acc[2][4] = {};

    auto stageA = [&](u16* dst, const u16* ta, int kel) {
        const u16* ga = ta + (size_t)sub * 1024 + kel + srck;
        gld_lds16(ga,             dst + wofs);
        gld_lds16(ga + 32 * 1024, dst + wofs + 2048);
    };
    auto stageB = [&](u16* dst, const u16* tb, int kel) {
        const u16* gb = tb + (size_t)sub * 3072 + kel + srck;
        gld_lds16(gb,             dst + wofs);
        gld_lds16(gb + 32 * 3072, dst + wofs + 2048);
        gld_lds16(gb + 64 * 3072, dst + wofs + 4096);
        gld_lds16(gb + 96 * 3072, dst + wofs + 6144);
    };
    auto step = [&](const u16* pfa, const u16* pfb, int kel, int do_pf) {
        __builtin_amdgcn_s_barrier();                       // (A)
        if (do_pf) {
            stageA(Ap, pfa, kel);
            stageB(Bp, pfb, kel);
            asm volatile("s_waitcnt vmcnt(6)" ::: "memory");
        } else {
            asm volatile("s_waitcnt vmcnt(0)" ::: "memory");
        }
        __builtin_amdgcn_s_barrier();                       // (B)

        short8 af[2][2], bfr[2][4];
#pragma unroll
        for (int kk = 0; kk < 2; ++kk) {
            const int so = (((kk << 2) | g16) ^ rsw) << 3;
#pragma unroll
            for (int fm = 0; fm < 2; ++fm)
                af[kk][fm] = *(const short8*)&Ac[(wr + fm * 16 + lrow) * 64 + so];
#pragma unroll
            for (int fn = 0; fn < 4; ++fn)
                bfr[kk][fn] = *(const short8*)&Bc[(wc + fn * 16 + lrow) * 64 + so];
        }
#pragma unroll
        for (int kk = 0; kk < 2; ++kk)
#pragma unroll
            for (int fm = 0; fm < 2; ++fm)
#pragma unroll
                for (int fn = 0; fn < 4; ++fn)
                    acc[fm][fn] = __builtin_amdgcn_mfma_f32_16x16x32_bf16(
                        af[kk][fm], bfr[kk][fn], acc[fm][fn], 0, 0, 0);
        u16* t;
        t = Ac; Ac = Ap; Ap = t;
        t = Bc; Bc = Bp; Bp = t;
    };
    auto run16 = [&](const u16* ta, const u16* tb,
                     const u16* na, const u16* nb, int hn) {
        for (int k = 1; k < 16; ++k) step(ta, tb, k << 6, 1);
        step(na, nb, 0, hn);
    };

    const size_t xbase = (size_t)col0 * 3072;
    const u16 *a0, *b0, *a1, *b1, *a2 = 0, *b2 = 0;
    int three = 0;
    if (i == 0) {
        a0 = Ab  + row0 * 1024; b0 = Xt + xbase;
        a1 = W0b + row0 * 1024; b1 = Xt + xbase + 1024;
    } else if (i == 1) {
        a0 = W0T + row0 * 1024; b0 = Xt + xbase;
        a1 = Ab  + row0 * 1024; b1 = Xt + xbase + 1024;
        a2 = W1b + row0 * 1024; b2 = Xt + xbase + 2048;
        three = 1;
    } else {
        a0 = W1T + row0 * 1024; b0 = Xt + xbase + 1024;
        a1 = Ab  + row0 * 1024; b1 = Xt + xbase + 2048;
    }

    stageA(Ac, a0, 0); stageB(Bc, b0, 0);
    run16(a0, b0, a1, b1, 1);
    if (three) { run16(a1, b1, a2, b2, 1); run16(a2, b2, 0, 0, 0); }
    else       { run16(a1, b1, 0, 0, 0); }

    // ---- epilogue: Wsm <- Wt (into A dbuf), Hsm <- bf16(acc) (into B dbuf)
    __syncthreads();
    u16* Wsm = Adb;
    u16* Hsm = Bdb;
#pragma unroll
    for (int p = 0; p < 4; ++p)
        gld_lds16(Wt + (size_t)(p * 32 + sub) * 64 + srck,
                  Adb + p * 2048 + wofs);
#pragma unroll
    for (int fm = 0; fm < 2; ++fm)
#pragma unroll
        for (int fn = 0; fn < 4; ++fn)
#pragma unroll
            for (int r = 0; r < 4; ++r) {
                const int n   = wr + fm * 16 + (g16 << 2) + r;
                const int col = wc + fn * 16 + lrow;
                const int sl2 = ((col >> 3) ^ (n & 7));
                Hsm[n * 128 + (sl2 << 3) + (col & 7)] = f2bf(acc[fm][fn][r]);
            }
    __syncthreads();

    // second GEMM: rows' = b*64+n (128), K = cin 64, N = 128 (lhs|rhs)
    f32x4 acc2[2][8];
#pragma unroll
    for (int fm2 = 0; fm2 < 2; ++fm2)
#pragma unroll
        for (int fn = 0; fn < 8; ++fn) {
            const float bv = Bias_sm[fn * 16 + lrow];
            acc2[fm2][fn] = (f32x4){bv, bv, bv, bv};
        }
#pragma unroll
    for (int kk = 0; kk < 2; ++kk) {
        const int gg = (kk << 2) | g16;
        short8 ah[2], bw[8];
#pragma unroll
        for (int fm2 = 0; fm2 < 2; ++fm2) {
            const int rowp = (w << 5) + (fm2 << 4) + lrow;
            const int b = rowp >> 6, n = rowp & 63;
            const int sl2 = ((b << 3) | gg) ^ (n & 7);
            ah[fm2] = *(const short8*)&Hsm[n * 128 + (sl2 << 3)];
        }
#pragma unroll
        for (int fn = 0; fn < 8; ++fn) {
            const int c = (fn << 4) + lrow;
            const int sl2 = gg ^ (c & 7);
            bw[fn] = *(const short8*)&Wsm[c * 64 + (sl2 << 3)];
        }
#pragma unroll
        for (int fm2 = 0; fm2 < 2; ++fm2)
#pragma unroll
            for (int fn = 0; fn < 8; ++fn)
                acc2[fm2][fn] = __builtin_amdgcn_mfma_f32_16x16x32_bf16(
                    ah[fm2], bw[fn], acc2[fm2][fn], 0, 0, 0);
    }

    const int n0g = i * 1024 + row0;
    const int b0i = nt << 1;
#pragma unroll
    for (int fm2 = 0; fm2 < 2; ++fm2)
#pragma unroll
        for (int fn = 0; fn < 4; ++fn)
#pragma unroll
            for (int r = 0; r < 4; ++r) {
                const int rowp = (w << 5) + (fm2 << 4) + (g16 << 2) + r;
                const int b = rowp >> 6, nl = rowp & 63;
                const float lhs = acc2[fm2][fn][r];
                const float rhs = acc2[fm2][fn + 4][r];
                const float sg  = 1.0f / (1.0f + __expf(-rhs));
                const int c = (fn << 4) + lrow;
                out[((size_t)(n0g + nl) * 32 + (b0i + b)) * 64 + c] = lhs * sg;
            }
}

// ---------------------------------------------------------------------------
extern "C" void kernel_launch(void* const* d_in, const int* in_sizes, int n_in,
                              void* d_out, int out_size, void* d_ws, size_t ws_size,
                              hipStream_t stream)
{
    const float* x    = (const float*)d_in[0];   // (3072, 32, 64)
    const float* adj  = (const float*)d_in[1];   // (1024, 1024)
    const float* wct  = (const float*)d_in[2];   // (2, 1024, 1024)
    const float* W    = (const float*)d_in[3];   // (64, 128)
    const float* bias = (const float*)d_in[4];   // (128,)
    float* out = (float*)d_out;

    char* ws = (char*)d_ws;
    u16* Xt  = (u16*)ws;                    // bf16 [2048][3072]
    u16* Ab  = (u16*)(ws + 12582912);       // 3 x 1M bf16 (Ab|W0b|W1b)
    u16* W0b = Ab + 1048576;
    u16* W1b = Ab + 2097152;
    u16* W0T = (u16*)(ws + 18874368);       // 2 x 1M bf16
    u16* W1T = W0T + 1048576;
    u16* Wt  = (u16*)(ws + 23068672);       // bf16 [128][64]

    prep_kernel<<<5122, 256, 0, stream>>>(x, adj, wct, W, Ab, W0T, W1T, Xt, Wt);
    gemm_h_kernel<<<768, 256, 0, stream>>>(Ab, W0b, W1b, W0T, W1T, Xt, Wt, bias, out);
}